// Round 8
// baseline (2536.228 us; speedup 1.0000x reference)
//
#include <hip/hip_runtime.h>
#include <hip/hip_bf16.h>

// RNNModule: leaky ReLU RNN scan + output projection, MI355X (gfx950).
// r8: explicit register-residency budget to eliminate scratch spills.
//     Per wave: 38 B-frags in AGPR (152) + 17 in LDS (152KB total w/ h tile)
//     + 9 streamed from a pre-packed global frag buffer each step (L2-hot,
//     3 batches of 3 inside the MFMA loop). Opaque-pointer asm stops the
//     compiler from hoisting stream loads into permanent registers.
//     Otherwise identical to r4 (16 blocks x 512 thr, single 16KB h buffer,
//     2 lgkm-only barriers/step, folded swizzle addressing).

typedef __attribute__((ext_vector_type(4))) float f32x4;
typedef __attribute__((ext_vector_type(8))) short s16x8;

constexpr int BB = 256, TT = 750, NN = 512, INN = 6, OUTN = 2, MLEN = 250;
constexpr int BBLK = 16;                 // batch rows per block
constexpr int NBLKS = BB / BBLK;         // 16 blocks, one per CU
constexpr int WPB = 8;                   // waves per block
constexpr int NSL = NN / WPB;            // 64 neurons per wave
constexpr int NREG = 38;                 // B-frags in AGPR (tt0,tt1,tt2:kk0-5)
constexpr int NLDSF = 17;                // B-frags in LDS  (f 38..54)
constexpr int NGLB = 9;                  // B-frags streamed (tt3: kk7..15)
constexpr int HBYTES = BBLK * NN * 2;    // 16 KB h tile (bf16, swizzled)
constexpr int WOFF = HBYTES;             // weights region start
constexpr int SMEM_BYTES = WOFF + WPB * NLDSF * 1024;  // 155648 B = 152 KB
constexpr int DRVELTS = NBLKS * WPB * 64 * 16;         // shorts per time step
constexpr size_t DRVTOT = (size_t)(TT - 1) * DRVELTS;  // shorts in drive buffer

__device__ __forceinline__ unsigned short f2bf(float f) {
    unsigned v = __float_as_uint(f);
    v += 0x7fffu + ((v >> 16) & 1u);     // RNE
    return (unsigned short)(v >> 16);
}
__device__ __forceinline__ float bf2f(unsigned short h) {
    return __uint_as_float(((unsigned)h) << 16);
}

// ---- pre-pass: drv[t][blk][wave][lane][16] bf16 = noise + u @ w_in^T ----
__global__ __launch_bounds__(256)
void drive_kernel(const float* __restrict__ u, const float* __restrict__ noise,
                  const float* __restrict__ w_in, unsigned short* __restrict__ drv)
{
    int gid = blockIdx.x * 256 + threadIdx.x;
    int t = gid >> 13;                           // 16 blk * 8 w * 64 lanes = 8192
    if (t >= TT - 1) return;
    int lane = gid & 63, w = (gid >> 6) & 7, blk = (gid >> 9) & 15;
    int qq = lane >> 4, lr = lane & 15;

    float wv[4][INN];
    #pragma unroll
    for (int tt = 0; tt < 4; ++tt) {
        int n = w * NSL + 16 * tt + lr;
        #pragma unroll
        for (int i = 0; i < INN; ++i) wv[tt][i] = w_in[n * INN + i];
    }
    alignas(16) unsigned short o[16];
    #pragma unroll
    for (int r = 0; r < 4; ++r) {
        int b = blk * BBLK + 4 * qq + r;
        const float* up = u + ((size_t)b * TT + t) * INN;
        float uv[INN];
        #pragma unroll
        for (int i = 0; i < INN; ++i) uv[i] = up[i];
        const float* np = noise + ((size_t)b * TT + t) * NN;
        #pragma unroll
        for (int tt = 0; tt < 4; ++tt) {
            int n = w * NSL + 16 * tt + lr;
            float d = np[n];
            #pragma unroll
            for (int i = 0; i < INN; ++i) d += uv[i] * wv[tt][i];
            o[tt * 4 + r] = f2bf(d);
        }
    }
    s16x8* dst = (s16x8*)(drv + (size_t)gid * 16);
    dst[0] = *(const s16x8*)&o[0];
    dst[1] = *(const s16x8*)&o[8];
}

// ---- pack streamed B-frags: gB[(w*9+i)*64+lane] = frag(tt=3, kk=7+i) ----
__global__ __launch_bounds__(256)
void packB_kernel(const float* __restrict__ w_rec, unsigned short* __restrict__ gB)
{
    int gid = blockIdx.x * 256 + threadIdx.x;    // 8 waves * 9 frags * 64 lanes
    if (gid >= WPB * NGLB * 64) return;
    int lane = gid & 63;
    int rem  = gid >> 6;                         // w*9 + i
    int w = rem / NGLB, i = rem - w * NGLB;
    int lr = lane & 15, qq = lane >> 4;
    int n = 64 * w + 48 + lr;                    // tt = 3
    int k = 32 * (7 + i) + 8 * qq;
    const float* p = w_rec + (size_t)n * NN + k;
    alignas(16) unsigned short o[8];
    #pragma unroll
    for (int j = 0; j < 8; ++j) o[j] = f2bf(p[j]);
    *(s16x8*)(gB + (size_t)gid * 8) = *(const s16x8*)&o[0];
}

// ---- persistent scan: 16 blocks x 8 waves, LDS-only h exchange ----
__global__ __launch_bounds__(512, 2)
void rnn_scan_kernel(const float* __restrict__ w_rec,
                     const unsigned short* __restrict__ drv,
                     const unsigned short* __restrict__ gB,
                     float* __restrict__ states)
{
    extern __shared__ char smem[];
    const int tid = threadIdx.x;
    const int w = tid >> 6, lane = tid & 63;
    const int qq = lane >> 4, lr = lane & 15, p7 = lr & 7;
    const int blk = blockIdx.x;
    const int bg = blk * BBLK;

    // stage weights: frag f=tt*16+kk: lane holds w_rec[n=64w+16tt+lr][32kk+8qq+j]
    // f < 38 -> AGPR; 38 <= f < 55 -> LDS slot m=f-38; f >= 55 -> streamed (skip)
    s16x8 breg[NREG];
    #pragma unroll
    for (int tt = 0; tt < 4; ++tt) {
        #pragma unroll
        for (int kk = 0; kk < 16; ++kk) {
            const int f = tt * 16 + kk;
            if (f >= NREG + NLDSF) continue;
            const int n = w * NSL + 16 * tt + lr;
            const float* p = w_rec + (size_t)n * NN + 32 * kk + 8 * qq;
            f32x4 x0 = *(const f32x4*)p;
            f32x4 x1 = *(const f32x4*)(p + 4);
            union { s16x8 v; unsigned short s[8]; } fr;
            #pragma unroll
            for (int j = 0; j < 4; ++j) { fr.s[j] = f2bf(x0[j]); fr.s[4+j] = f2bf(x1[j]); }
            if (f < NREG) breg[f] = fr.v;
            else *(s16x8*)(smem + WOFF + (w * NLDSF + (f - NREG)) * 1024 + lane * 16) = fr.v;
        }
    }
    // zero h buffer (h_0 = 0) and states[:,0,:] for our rows
    for (int i = tid; i < HBYTES / 4; i += 512) ((unsigned*)smem)[i] = 0u;
    for (int i = tid; i < BBLK * NN; i += 512)
        states[(size_t)(bg + (i >> 9)) * TT * NN + (i & 511)] = 0.f;
    __syncthreads();

    float stl[16];
    #pragma unroll
    for (int i = 0; i < 16; ++i) stl[i] = 0.f;

    // A-read folded bases: addr(kk) = lr*1024 + ((4kk+qq)^p7)<<4 = base(E/O) + 64kk
    const int rb64 = (p7 & 4) << 4;
    const int hbase0 = lr * 1024 + ((qq ^ (p7 & 3)) << 4);
    const char* hbE = smem + hbase0 + rb64;
    const char* hbO = smem + hbase0 - rb64;
    const char* wbase = smem + WOFF + w * (NLDSF * 1024) + lane * 16;

    // h-write folded base: addr(tt,r) = (LB ^ (((2tt)^r)<<4)) + 1024r
    const int s0 = 8 * w + (lr >> 3);
    const unsigned LB = 4096u * qq + ((unsigned)(s0 ^ (4 * (qq & 1))) << 4) + 2 * (lr & 7);

    float* rowp[4];
    #pragma unroll
    for (int r = 0; r < 4; ++r)
        rowp[r] = states + ((size_t)(bg + 4 * qq + r) * TT + 1) * NN + w * NSL + lr;

    const unsigned short* dptr = drv + ((size_t)(blk * WPB + w) * 64 + lane) * 16;
    // streamed-frag base: frag i at gq + i*1024 bytes
    const char* gq = (const char*)gB + ((size_t)(w * NGLB) * 64 + lane) * 16;

    for (int s = 1; s < TT; ++s) {
        // opaque pointer: stops hoisting stream loads out of the loop
        asm volatile("" : "+v"(gq));
        const s16x8* dp = (const s16x8*)dptr;
        s16x8 dv0 = dp[0], dv1 = dp[1];
        dptr += DRVELTS;

        f32x4 a0 = {0.f,0.f,0.f,0.f}, a1 = a0, a2 = a0, a3 = a0;
        s16x8 gb[NGLB];

        #pragma unroll
        for (int kk = 0; kk < 16; ++kk) {
            // stream batches of 3, issued >=6 MFMA-quads before consumption
            if (kk == 0) {
                gb[0] = *(const s16x8*)(gq);
                gb[1] = *(const s16x8*)(gq + 1024);
                gb[2] = *(const s16x8*)(gq + 2048);
            }
            if (kk == 4) {
                gb[3] = *(const s16x8*)(gq + 3072);
                gb[4] = *(const s16x8*)(gq + 4096);
                gb[5] = *(const s16x8*)(gq + 5120);
            }
            if (kk == 8) {
                gb[6] = *(const s16x8*)(gq + 6144);
                gb[7] = *(const s16x8*)(gq + 7168);
                gb[8] = *(const s16x8*)(gq + 8192);
            }
            s16x8 av = *(const s16x8*)(((kk & 1) ? hbO : hbE) + (kk << 6));
            a0 = __builtin_amdgcn_mfma_f32_16x16x32_bf16(av, breg[kk],      a0, 0,0,0);
            a1 = __builtin_amdgcn_mfma_f32_16x16x32_bf16(av, breg[16 + kk], a1, 0,0,0);
            if (kk < 6)
                a2 = __builtin_amdgcn_mfma_f32_16x16x32_bf16(av, breg[32+kk], a2, 0,0,0);
            else
                a2 = __builtin_amdgcn_mfma_f32_16x16x32_bf16(
                         av, *(const s16x8*)(wbase + ((kk - 6) << 10)), a2, 0, 0, 0);
            if (kk < 7)
                a3 = __builtin_amdgcn_mfma_f32_16x16x32_bf16(
                         av, *(const s16x8*)(wbase + ((10 + kk) << 10)), a3, 0, 0, 0);
            else
                a3 = __builtin_amdgcn_mfma_f32_16x16x32_bf16(av, gb[kk - 7], a3, 0,0,0);
        }

        // ---- epilogue: compute + NT store + pack BEFORE the read-drain
        //      barrier; only LDS h-writes wait for it ----
        union { s16x8 v; unsigned short e[8]; } U0, U1;
        U0.v = dv0; U1.v = dv1;
        const f32x4 aP[4] = {a0, a1, a2, a3};
        unsigned pk[8];
        #pragma unroll
        for (int p = 0; p < 2; ++p) {
            #pragma unroll
            for (int r = 0; r < 4; ++r) {
                float dE = bf2f(p == 0 ? U0.e[r]     : U1.e[r]);
                float dO = bf2f(p == 0 ? U0.e[4 + r] : U1.e[4 + r]);
                float hE = 0.8f * stl[(2*p)*4 + r]   + 0.2f * fmaxf(aP[2*p][r]   + dE, 0.f);
                float hO = 0.8f * stl[(2*p+1)*4 + r] + 0.2f * fmaxf(aP[2*p+1][r] + dO, 0.f);
                stl[(2*p)*4 + r] = hE;
                stl[(2*p+1)*4 + r] = hO;
                __builtin_nontemporal_store(hE, rowp[r] + (2*p) * 16);
                __builtin_nontemporal_store(hO, rowp[r] + (2*p+1) * 16);
                __hip_bfloat162 h2 = __float22bfloat162_rn(make_float2(hE, hO));
                pk[p * 4 + r] = *reinterpret_cast<unsigned*>(&h2);
            }
        }
        #pragma unroll
        for (int r = 0; r < 4; ++r) rowp[r] += NN;

        // barrier 1: all waves' A-reads drained -> safe to overwrite h
        asm volatile("s_waitcnt lgkmcnt(0)\n\ts_barrier" ::: "memory");

        #pragma unroll
        for (int tt = 0; tt < 4; ++tt) {
            #pragma unroll
            for (int r = 0; r < 4; ++r) {
                const unsigned C = (unsigned)(((2 * tt) ^ r) << 4);
                unsigned short hv = (tt & 1) ? (unsigned short)(pk[(tt >> 1) * 4 + r] >> 16)
                                             : (unsigned short)(pk[(tt >> 1) * 4 + r]);
                *(unsigned short*)(smem + ((LB ^ C) + 1024 * r)) = hv;
            }
        }
        // barrier 2: h writes visible -> next step may read
        asm volatile("s_waitcnt lgkmcnt(0)\n\ts_barrier" ::: "memory");
    }
}

// out[b,t,o] = sum_n states[b,t,n] * w_out[o,n]; one wave per (b,t) row
__global__ __launch_bounds__(256)
void proj_kernel(const float* __restrict__ states, const float* __restrict__ w_out,
                 float* __restrict__ outf)
{
    const int wv   = (blockIdx.x * blockDim.x + threadIdx.x) >> 6;
    const int lane = threadIdx.x & 63;
    const float* sp = states + (size_t)wv * NN + lane * 8;
    const float* w0 = w_out + lane * 8;
    const float* w1 = w_out + NN + lane * 8;
    float d0 = 0.f, d1 = 0.f;
    #pragma unroll
    for (int i = 0; i < 8; ++i) {
        float sv = sp[i];
        d0 += sv * w0[i];
        d1 += sv * w1[i];
    }
    #pragma unroll
    for (int off = 32; off > 0; off >>= 1) {
        d0 += __shfl_xor(d0, off);
        d1 += __shfl_xor(d1, off);
    }
    if (lane == 0) {
        outf[(size_t)wv * 2]     = d0;
        outf[(size_t)wv * 2 + 1] = d1;
    }
}

__global__ void mask_kernel(const int* __restrict__ mask, const float* __restrict__ outf,
                            float* __restrict__ outm)
{
    int idx = blockIdx.x * blockDim.x + threadIdx.x;
    if (idx >= BB * MLEN * OUTN) return;
    int o  = idx % OUTN;
    int jm = (idx / OUTN) % MLEN;
    int b  = idx / (OUTN * MLEN);
    int t  = mask[jm];
    outm[idx] = outf[((size_t)b * TT + t) * OUTN + o];
}

extern "C" void kernel_launch(void* const* d_in, const int* in_sizes, int n_in,
                              void* d_out, int out_size, void* d_ws, size_t ws_size,
                              hipStream_t stream)
{
    (void)in_sizes; (void)n_in; (void)out_size; (void)ws_size;
    const float* u     = (const float*)d_in[0];
    const float* noise = (const float*)d_in[1];
    const float* w_rec = (const float*)d_in[2];
    const float* w_in  = (const float*)d_in[3];
    const float* w_out = (const float*)d_in[4];
    const int*   mask  = (const int*)d_in[5];

    float* states = (float*)d_out;                          // [256][750][512]
    float* outm   = states + (size_t)BB * TT * NN;          // [256][250][2]
    float* outf   = outm + (size_t)BB * MLEN * OUTN;        // [256][750][2]

    unsigned short* drvpk = (unsigned short*)d_ws;          // 196.3 MB packed drive
    unsigned short* gB    = drvpk + DRVTOT;                 // 73.7 KB packed B-frags

    hipFuncSetAttribute((const void*)rnn_scan_kernel,
                        hipFuncAttributeMaxDynamicSharedMemorySize, SMEM_BYTES);

    drive_kernel<<<(TT - 1) * 32, 256, 0, stream>>>(u, noise, w_in, drvpk);
    packB_kernel<<<(WPB * NGLB * 64 + 255) / 256, 256, 0, stream>>>(w_rec, gB);
    rnn_scan_kernel<<<NBLKS, 512, SMEM_BYTES, stream>>>(w_rec, drvpk, gB, states);
    proj_kernel<<<(BB * TT) / 4, 256, 0, stream>>>(states, w_out, outf);
    mask_kernel<<<(BB * MLEN * OUTN + 255) / 256, 256, 0, stream>>>(mask, outf, outm);
}